// Round 7
// baseline (330.410 us; speedup 1.0000x reference)
//
#include <hip/hip_runtime.h>
#include <stdint.h>

// Problem constants: B=8, N=2048, F_in=F_out=512
#define NB 8
#define NN 2048
#define NF 512
#define TOTN (NB * NN)   // 16384 nodes total

typedef unsigned short u16;
typedef short bf16x8 __attribute__((ext_vector_type(8)));
typedef float f32x4 __attribute__((ext_vector_type(4)));

__device__ __forceinline__ u16 f2bf(float x) {
  unsigned u = __float_as_uint(x);
  unsigned r = 0x7FFFu + ((u >> 16) & 1u);
  return (u16)((u + r) >> 16);
}

__device__ __forceinline__ float felem(float4 q, int e) {
  // e is an unroll-time constant; folds to a plain register pick
  return (e == 0) ? q.x : (e == 1) ? q.y : (e == 2) ? q.z : q.w;
}

__device__ __forceinline__ void gl2lds16(const void* g, void* l) {
  __builtin_amdgcn_global_load_lds((const __attribute__((address_space(1))) void*)g,
                                   (__attribute__((address_space(3))) void*)l,
                                   16, 0, 0);
}

// Bg layout (B-operand frag-major): [z 8][ot 4][kc 64][jf 8][lane 64][8 u16]
//   lane = kq*16 + oln holds B[o = ot*128 + jf*16 + oln][k = kc*32 + kq*8 ..+8]
// bmT layout (transposed bitmask): [z 8][col 64][row 2048] u32 — a wave's mask
//   load for 16 consecutive rows is one 64 B line (no gather).

// ---------------------------------------------------------------------------
// K1: convert text (8.4M fp32) -> bf16, and W -> W^T bf16.
// ---------------------------------------------------------------------------
__global__ __launch_bounds__(256) void conv_kernel(
    const float* __restrict__ text, const float* __restrict__ W,
    u16* __restrict__ text_bf, u16* __restrict__ Wt) {
  int blk = blockIdx.x;
  if (blk < 8192) {
    int idx = blk * 256 + threadIdx.x;
    float4 v = ((const float4*)text)[idx];
    ushort4 o;
    o.x = f2bf(v.x); o.y = f2bf(v.y); o.z = f2bf(v.z); o.w = f2bf(v.w);
    ((ushort4*)text_bf)[idx] = o;
  } else {
    int t = (blk - 8192) * 256 + threadIdx.x;
    int o = t >> 9, f = t & 511;
    Wt[o * NF + f] = f2bf(W[f * NF + o]);
  }
}

// ---------------------------------------------------------------------------
// K2: pack adj (int32 0/1) -> TRANSPOSED bitmask bmT[z][col 64][row 2048].
// Reads coalesced (row-major); 4 B writes scatter but land in L2 (4 MB total).
// ---------------------------------------------------------------------------
__global__ __launch_bounds__(256) void pack_kernel(
    const int* __restrict__ adj, uint32_t* __restrict__ bmT) {
  int bid = blockIdx.x;               // 4096 blocks
  int z = bid & 7, idx = bid >> 3;
  int widx = idx * 256 + threadIdx.x; // row-major word index within z
  int row = widx >> 6, col = widx & 63;
  const int4* p = (const int4*)(adj + ((size_t)z * 131072 + widx) * 32);
  uint32_t bits = 0;
#pragma unroll
  for (int c = 0; c < 8; ++c) {
    int4 a = p[c];
    bits |= (uint32_t)(a.x != 0) << (c * 4 + 0);
    bits |= (uint32_t)(a.y != 0) << (c * 4 + 1);
    bits |= (uint32_t)(a.z != 0) << (c * 4 + 2);
    bits |= (uint32_t)(a.w != 0) << (c * 4 + 3);
  }
  bmT[z * 131072 + col * 2048 + row] = bits;
}

// ---------------------------------------------------------------------------
// K3: GEMM1 hidden -> Bg fragment-major layout + fused s/d score epilogue.
// ---------------------------------------------------------------------------
__global__ __launch_bounds__(256) void gemm1_kernel(
    const u16* __restrict__ A,   // Wt [512][512]
    const u16* __restrict__ Bt,  // text_bf [16384][512]
    const float* __restrict__ bias, const float* __restrict__ a_src,
    const float* __restrict__ a_dst, u16* __restrict__ Bg,
    float* __restrict__ s, float* __restrict__ d) {
  __shared__ u16 Alds[128 * 32];
  __shared__ u16 Blds[128 * 32];

  const int bid = blockIdx.x;                  // 512 blocks
  const int zx = bid & 7, u = (bid >> 3) & 15, bm_ = bid >> 7;
  const int bn = zx * 16 + u;
  const int t = threadIdx.x, wave = t >> 6, lane = t & 63;
  const int wm = (wave >> 1) * 64, wn = (wave & 1) * 64;

  f32x4 acc[4][4];
#pragma unroll
  for (int i = 0; i < 4; ++i)
#pragma unroll
    for (int j = 0; j < 4; ++j) acc[i][j] = (f32x4){0.f, 0.f, 0.f, 0.f};

  const int rowA0 = bm_ * 128, rowB0 = bn * 128;
  const int srow = (lane >> 2);
  const int scol = (lane & 3) * 8;

  for (int kt = 0; kt < NF; kt += 32) {
#pragma unroll
    for (int q = 0; q < 2; ++q) {
      int r = wave * 32 + q * 16;
      gl2lds16(A + (size_t)(rowA0 + r + srow) * NF + (kt + scol), &Alds[r * 32]);
    }
#pragma unroll
    for (int q = 0; q < 2; ++q) {
      int r = wave * 32 + q * 16;
      gl2lds16(Bt + (size_t)(rowB0 + r + srow) * NF + (kt + scol), &Blds[r * 32]);
    }
    __syncthreads();

    const int fr = lane & 15;
    const int k0 = (lane >> 4) * 8;
    bf16x8 af[4], bfr[4];
#pragma unroll
    for (int i = 0; i < 4; ++i)
      af[i] = *(const bf16x8*)&Alds[(wm + i * 16 + fr) * 32 + k0];
#pragma unroll
    for (int j = 0; j < 4; ++j)
      bfr[j] = *(const bf16x8*)&Blds[(wn + j * 16 + fr) * 32 + k0];
#pragma unroll
    for (int i = 0; i < 4; ++i)
#pragma unroll
      for (int j = 0; j < 4; ++j)
        acc[i][j] = __builtin_amdgcn_mfma_f32_16x16x32_bf16(af[i], bfr[j],
                                                            acc[i][j], 0, 0, 0);
    __syncthreads();
  }

  const int quad = lane >> 4, ln16 = lane & 15;
  float sa[4] = {0.f, 0.f, 0.f, 0.f}, da[4] = {0.f, 0.f, 0.f, 0.f};
#pragma unroll
  for (int i = 0; i < 4; ++i) {
    int m0 = bm_ * 128 + wm + i * 16 + quad * 4;
#pragma unroll
    for (int r = 0; r < 4; ++r) {
      int m = m0 + r;
      float bv = bias[m];
      float asv = a_src[m], adv = a_dst[m];
      int otp = m >> 7, jf = (m >> 4) & 7, oln = m & 15;
#pragma unroll
      for (int j = 0; j < 4; ++j) {
        int n = bn * 128 + wn + j * 16 + ln16;
        float h = acc[i][j][r] + bv;
        int zz = n >> 11, nz = n & 2047;
        int kc = nz >> 5, kq = (nz >> 3) & 3, ke = nz & 7;
        size_t off = (((size_t)zz * 4 + otp) << 18) + (kc << 12) + (jf << 9) +
                     ((kq * 16 + oln) << 3) + ke;
        Bg[off] = f2bf(h);
        sa[j] = fmaf(h, asv, sa[j]);
        da[j] = fmaf(h, adv, da[j]);
      }
    }
  }
#pragma unroll
  for (int j = 0; j < 4; ++j) {
    float v = sa[j] + __shfl_xor(sa[j], 16, 64);
    v += __shfl_xor(v, 32, 64);
    float w2 = da[j] + __shfl_xor(da[j], 16, 64);
    w2 += __shfl_xor(w2, 32, 64);
    if (quad == 0) {
      int n = bn * 128 + wn + j * 16 + ln16;
      atomicAdd(&s[n], v);
      atomicAdd(&d[n], w2);
    }
  }
}

// ---------------------------------------------------------------------------
// K4 (fused, BARRIER-FREE): out[z,i,o] = (1/l_i)*sum_j P(i,j)*h[j][o]
// A-fragments computed per-lane IN REGISTERS (no LDS, no __syncthreads in
// the K-loop). Wave tile 64i x 128o; block = 4 waves = 256i x 128o; grid
// 8z x 8it x 4ot = 256 blocks (1/CU, 1 wave/SIMD, ~280 VGPR).
// Waves free-run: B-loads issue first, P-gen VALU hides their latency.
// ---------------------------------------------------------------------------
__global__ __launch_bounds__(256, 1) void fused_attn_kernel(
    const uint32_t* __restrict__ bmT, const float* __restrict__ s,
    const float* __restrict__ d, const u16* __restrict__ Bg,
    float* __restrict__ out) {
  __shared__ float linv_lds[4][64];

  const int bid = blockIdx.x;      // 256 blocks
  const int z = bid & 7;
  const int rest = bid >> 3;       // 0..31
  const int it = rest & 7, ot = rest >> 3;
  const int t = threadIdx.x, wave = t >> 6, lane = t & 63;
  const int quad = lane >> 4, ln16 = lane & 15;
  const int i0w = it * 256 + wave * 64;   // wave's first i row

  const float* sz = s + z * NN;
  const float* dz = d + z * NN;
  const uint32_t* bmz = bmT + z * 131072;
  const u16* BgW = Bg + (((size_t)z * 4 + ot) << 18);

  // preload s for the wave's 4 i-frag rows this lane owns
  float si[4];
  int rowv[4];
#pragma unroll
  for (int f = 0; f < 4; ++f) {
    rowv[f] = i0w + f * 16 + ln16;
    si[f] = sz[rowv[f]];
  }

  f32x4 acc[4][8];
#pragma unroll
  for (int f = 0; f < 4; ++f)
#pragma unroll
    for (int j = 0; j < 8; ++j) acc[f][j] = (f32x4){0.f, 0.f, 0.f, 0.f};

  float lsum[4] = {0.f, 0.f, 0.f, 0.f};

  // prefetch mask words + d values for kt=0
  uint32_t wcur[4][2];
  float4 dcur[4];
#pragma unroll
  for (int f = 0; f < 4; ++f) {
    wcur[f][0] = bmz[0 * 2048 + rowv[f]];
    wcur[f][1] = bmz[1 * 2048 + rowv[f]];
  }
#pragma unroll
  for (int h = 0; h < 2; ++h)
#pragma unroll
    for (int c = 0; c < 2; ++c)
      dcur[h * 2 + c] = *(const float4*)&dz[h * 32 + quad * 8 + c * 4];

  for (int kt = 0; kt < NN; kt += 64) {
    const int kc0 = kt >> 5;

    // ---- 1. issue B-frag loads (16 x dwordx4, L1/L2-hot) ----
    bf16x8 bfr[2][8];
#pragma unroll
    for (int h = 0; h < 2; ++h)
#pragma unroll
      for (int j = 0; j < 8; ++j)
        bfr[h][j] = *(const bf16x8*)&BgW[(size_t)(kc0 + h) * 4096 + j * 512 +
                                         lane * 8];

    // ---- 2. P-gen in registers (VALU; overlaps B-load latency) ----
    bf16x8 af[2][4];
#pragma unroll
    for (int f = 0; f < 4; ++f) {
#pragma unroll
      for (int h = 0; h < 2; ++h) {
        uint32_t bits = wcur[f][h] >> (quad * 8);
#pragma unroll
        for (int e = 0; e < 8; ++e) {
          float dj = felem(dcur[h * 2 + (e >> 2)], e & 3);
          float x = si[f] + dj;
          float xm = fmaxf(x, 0.2f * x);
          float p = ((bits >> e) & 1u) ? 0.f : __expf(xm);
          lsum[f] += p;
          af[h][f][e] = (short)((__float_as_uint(p) + 0x8000u) >> 16);
        }
      }
    }

    // ---- 3. prefetch next iter's mask/d ----
    if (kt + 64 < NN) {
      int c0 = (kt + 64) >> 5;
#pragma unroll
      for (int f = 0; f < 4; ++f) {
        wcur[f][0] = bmz[(c0 + 0) * 2048 + rowv[f]];
        wcur[f][1] = bmz[(c0 + 1) * 2048 + rowv[f]];
      }
#pragma unroll
      for (int h = 0; h < 2; ++h)
#pragma unroll
        for (int c = 0; c < 2; ++c)
          dcur[h * 2 + c] =
              *(const float4*)&dz[kt + 64 + h * 32 + quad * 8 + c * 4];
    }

    // ---- 4. MFMA: 2 halves x 4 i-frags x 8 j-frags ----
#pragma unroll
    for (int h = 0; h < 2; ++h)
#pragma unroll
      for (int f = 0; f < 4; ++f)
#pragma unroll
        for (int j = 0; j < 8; ++j)
          acc[f][j] = __builtin_amdgcn_mfma_f32_16x16x32_bf16(af[h][f],
                                                              bfr[h][j],
                                                              acc[f][j], 0, 0, 0);
  }

  // ---- row sums: allreduce across quads, then 1/l via per-wave LDS ----
#pragma unroll
  for (int f = 0; f < 4; ++f) {
    lsum[f] += __shfl_xor(lsum[f], 16, 64);
    lsum[f] += __shfl_xor(lsum[f], 32, 64);
    if (quad == 0) linv_lds[wave][f * 16 + ln16] = 1.0f / lsum[f];
  }
  __syncthreads();  // only barrier in the kernel (epilogue handoff)

  // ---- epilogue: C/D layout col=ln16 (o), row=quad*4+r (i) ----
#pragma unroll
  for (int f = 0; f < 4; ++f) {
#pragma unroll
    for (int r = 0; r < 4; ++r) {
      int m = f * 16 + quad * 4 + r;
      float sc = linv_lds[wave][m];
      float* ob = out + ((size_t)(z * NN) + i0w + m) * NF + ot * 128;
#pragma unroll
      for (int j = 0; j < 8; ++j) ob[j * 16 + ln16] = acc[f][j][r] * sc;
    }
  }
}

// ---------------------------------------------------------------------------
// launch
// ---------------------------------------------------------------------------
extern "C" void kernel_launch(void* const* d_in, const int* in_sizes, int n_in,
                              void* d_out, int out_size, void* d_ws,
                              size_t ws_size, hipStream_t stream) {
  const float* text  = (const float*)d_in[0];   // [8,2048,512] fp32
  const int*   adj   = (const int*)d_in[1];     // [8,2048,2048] int32
  const float* W     = (const float*)d_in[2];   // [512,512] fp32
  const float* bias  = (const float*)d_in[3];   // [512] fp32
  const float* a_src = (const float*)d_in[4];   // [512] fp32
  const float* a_dst = (const float*)d_in[5];   // [512] fp32
  float* out = (float*)d_out;                   // [8,2048,512] fp32

  // ws layout (bytes), ~38.4 MB
  char* ws = (char*)d_ws;
  u16*      text_bf = (u16*)(ws + 0);            // 16,777,216
  u16*      Wt      = (u16*)(ws + 16777216);     //    524,288
  u16*      Bg      = (u16*)(ws + 17301504);     // 16,777,216  frag-major
  float*    s       = (float*)(ws + 34078720);   //     65,536
  float*    d       = (float*)(ws + 34144256);   //     65,536
  uint32_t* bmT     = (uint32_t*)(ws + 34209792);// 4,194,304   transposed bits

  hipMemsetAsync(s, 0, 131072, stream);          // zero s,d (contiguous)

  conv_kernel<<<9216, 256, 0, stream>>>(text, W, text_bf, Wt);
  pack_kernel<<<4096, 256, 0, stream>>>(adj, bmT);

  gemm1_kernel<<<512, 256, 0, stream>>>(Wt, text_bf, bias, a_src, a_dst, Bg, s, d);

  fused_attn_kernel<<<256, 256, 0, stream>>>(bmT, s, d, Bg, out);
}

// Round 8
// 310.263 us; speedup vs baseline: 1.0649x; 1.0649x over previous
//
#include <hip/hip_runtime.h>
#include <stdint.h>

// Problem constants: B=8, N=2048, F_in=F_out=512
#define NB 8
#define NN 2048
#define NF 512
#define TOTN (NB * NN)   // 16384 nodes total

typedef unsigned short u16;
typedef short bf16x8 __attribute__((ext_vector_type(8)));
typedef float f32x4 __attribute__((ext_vector_type(4)));

__device__ __forceinline__ u16 f2bf(float x) {
  unsigned u = __float_as_uint(x);
  unsigned r = 0x7FFFu + ((u >> 16) & 1u);
  return (u16)((u + r) >> 16);
}

__device__ __forceinline__ float felem(float4 q, int e) {
  return (e == 0) ? q.x : (e == 1) ? q.y : (e == 2) ? q.z : q.w;
}

__device__ __forceinline__ void gl2lds16(const void* g, void* l) {
  __builtin_amdgcn_global_load_lds((const __attribute__((address_space(1))) void*)g,
                                   (__attribute__((address_space(3))) void*)l,
                                   16, 0, 0);
}

// Bg layout (B-operand frag-major, verified R5): [z 8][kc 64][of 32][lane 64][8]
//   lane = kq*16 + oln holds B[o = of*16+oln][k = kc*32 + kq*8 ..+8]
// bmT layout (transposed bitmask, verified R7): [z 8][col 64][row 2048] u32.
// P LDS swizzle (verified R3-R6): 16-row chunk, (row rc, k-quarter q) ->
//   slot = rc*4 + (q ^ ((rc>>1)&3)), 16 B/slot; frag read at
//   fslot = ln16*4 + (quad ^ ((ln16>>1)&3)).

// ---------------------------------------------------------------------------
// K1: convert text (8.4M fp32) -> bf16, and W -> W^T bf16.
// ---------------------------------------------------------------------------
__global__ __launch_bounds__(256) void conv_kernel(
    const float* __restrict__ text, const float* __restrict__ W,
    u16* __restrict__ text_bf, u16* __restrict__ Wt) {
  int blk = blockIdx.x;
  if (blk < 8192) {
    int idx = blk * 256 + threadIdx.x;
    float4 v = ((const float4*)text)[idx];
    ushort4 o;
    o.x = f2bf(v.x); o.y = f2bf(v.y); o.z = f2bf(v.z); o.w = f2bf(v.w);
    ((ushort4*)text_bf)[idx] = o;
  } else {
    int t = (blk - 8192) * 256 + threadIdx.x;
    int o = t >> 9, f = t & 511;
    Wt[o * NF + f] = f2bf(W[f * NF + o]);
  }
}

// ---------------------------------------------------------------------------
// K2: pack adj (int32 0/1) -> TRANSPOSED bitmask bmT[z][col 64][row 2048].
// ---------------------------------------------------------------------------
__global__ __launch_bounds__(256) void pack_kernel(
    const int* __restrict__ adj, uint32_t* __restrict__ bmT) {
  int bid = blockIdx.x;               // 4096 blocks
  int z = bid & 7, idx = bid >> 3;
  int widx = idx * 256 + threadIdx.x; // row-major word index within z
  int row = widx >> 6, col = widx & 63;
  const int4* p = (const int4*)(adj + ((size_t)z * 131072 + widx) * 32);
  uint32_t bits = 0;
#pragma unroll
  for (int c = 0; c < 8; ++c) {
    int4 a = p[c];
    bits |= (uint32_t)(a.x != 0) << (c * 4 + 0);
    bits |= (uint32_t)(a.y != 0) << (c * 4 + 1);
    bits |= (uint32_t)(a.z != 0) << (c * 4 + 2);
    bits |= (uint32_t)(a.w != 0) << (c * 4 + 3);
  }
  bmT[z * 131072 + col * 2048 + row] = bits;
}

// ---------------------------------------------------------------------------
// K3: GEMM1 hidden -> Bg fragment-major layout + fused s/d score epilogue.
// ---------------------------------------------------------------------------
__global__ __launch_bounds__(256) void gemm1_kernel(
    const u16* __restrict__ A,   // Wt [512][512]
    const u16* __restrict__ Bt,  // text_bf [16384][512]
    const float* __restrict__ bias, const float* __restrict__ a_src,
    const float* __restrict__ a_dst, u16* __restrict__ Bg,
    float* __restrict__ s, float* __restrict__ d) {
  __shared__ u16 Alds[128 * 32];
  __shared__ u16 Blds[128 * 32];

  const int bid = blockIdx.x;                  // 512 blocks
  const int zx = bid & 7, u = (bid >> 3) & 15, bm_ = bid >> 7;
  const int bn = zx * 16 + u;
  const int t = threadIdx.x, wave = t >> 6, lane = t & 63;
  const int wm = (wave >> 1) * 64, wn = (wave & 1) * 64;

  f32x4 acc[4][4];
#pragma unroll
  for (int i = 0; i < 4; ++i)
#pragma unroll
    for (int j = 0; j < 4; ++j) acc[i][j] = (f32x4){0.f, 0.f, 0.f, 0.f};

  const int rowA0 = bm_ * 128, rowB0 = bn * 128;
  const int srow = (lane >> 2);
  const int scol = (lane & 3) * 8;

  for (int kt = 0; kt < NF; kt += 32) {
#pragma unroll
    for (int q = 0; q < 2; ++q) {
      int r = wave * 32 + q * 16;
      gl2lds16(A + (size_t)(rowA0 + r + srow) * NF + (kt + scol), &Alds[r * 32]);
    }
#pragma unroll
    for (int q = 0; q < 2; ++q) {
      int r = wave * 32 + q * 16;
      gl2lds16(Bt + (size_t)(rowB0 + r + srow) * NF + (kt + scol), &Blds[r * 32]);
    }
    __syncthreads();

    const int fr = lane & 15;
    const int k0 = (lane >> 4) * 8;
    bf16x8 af[4], bfr[4];
#pragma unroll
    for (int i = 0; i < 4; ++i)
      af[i] = *(const bf16x8*)&Alds[(wm + i * 16 + fr) * 32 + k0];
#pragma unroll
    for (int j = 0; j < 4; ++j)
      bfr[j] = *(const bf16x8*)&Blds[(wn + j * 16 + fr) * 32 + k0];
#pragma unroll
    for (int i = 0; i < 4; ++i)
#pragma unroll
      for (int j = 0; j < 4; ++j)
        acc[i][j] = __builtin_amdgcn_mfma_f32_16x16x32_bf16(af[i], bfr[j],
                                                            acc[i][j], 0, 0, 0);
    __syncthreads();
  }

  const int quad = lane >> 4, ln16 = lane & 15;
  float sa[4] = {0.f, 0.f, 0.f, 0.f}, da[4] = {0.f, 0.f, 0.f, 0.f};
#pragma unroll
  for (int i = 0; i < 4; ++i) {
    int m0 = bm_ * 128 + wm + i * 16 + quad * 4;
#pragma unroll
    for (int r = 0; r < 4; ++r) {
      int m = m0 + r;
      float bv = bias[m];
      float asv = a_src[m], adv = a_dst[m];
      int oc = m >> 4, oln = m & 15;
#pragma unroll
      for (int j = 0; j < 4; ++j) {
        int n = bn * 128 + wn + j * 16 + ln16;
        float h = acc[i][j][r] + bv;
        int zz = n >> 11, nz = n & 2047;
        int kc = nz >> 5, kq = (nz >> 3) & 3, ke = nz & 7;
        size_t off = ((size_t)zz << 20) + (((size_t)kc * 32 + oc) << 9) +
                     ((kq * 16 + oln) << 3) + ke;
        Bg[off] = f2bf(h);
        sa[j] = fmaf(h, asv, sa[j]);
        da[j] = fmaf(h, adv, da[j]);
      }
    }
  }
#pragma unroll
  for (int j = 0; j < 4; ++j) {
    float v = sa[j] + __shfl_xor(sa[j], 16, 64);
    v += __shfl_xor(v, 32, 64);
    float w2 = da[j] + __shfl_xor(da[j], 16, 64);
    w2 += __shfl_xor(w2, 32, 64);
    if (quad == 0) {
      int n = bn * 128 + wn + j * 16 + ln16;
      atomicAdd(&s[n], v);
      atomicAdd(&d[n], w2);
    }
  }
}

// ---------------------------------------------------------------------------
// K4 (fused v8): out[z,i,o] = (1/l_i)*sum_j P(i,j)*h[j][o]
// Block 256 thr / 4 waves, tile 64i x 256o (wave 64i x 64o). P computed
// COOPERATIVELY once per block (16 exps/thread), double-buffered LDS,
// ONE barrier per BK=64 iter. B-frags direct global->VGPR (frag-major Bg).
// Grid 8z x 32it x 2ot = 512 blocks => 2 blocks/CU, 2 waves/SIMD.
// ---------------------------------------------------------------------------
__global__ __launch_bounds__(256, 2) void fused_attn_kernel(
    const uint32_t* __restrict__ bmT, const float* __restrict__ s,
    const float* __restrict__ d, const u16* __restrict__ Bg,
    float* __restrict__ out) {
  __shared__ u16 Plds[2][4096];   // [parity][half 2][chunk 4][slot 64][8]
  __shared__ float lpart[256];
  __shared__ float linv_lds[64];

  const int bid = blockIdx.x;     // 512 blocks
  const int z = bid & 7;
  const int rest = bid >> 3;      // 0..63
  const int it = rest & 31, ot = rest >> 5;
  const int i0 = it * 64;
  const int t = threadIdx.x, wave = t >> 6, lane = t & 63;
  const int quad = lane >> 4, ln16 = lane & 15;

  // P-gen mapping: 4 threads per i-row, 16 k each
  const int pr = t >> 2;          // 0..63
  const int ks = (t & 3) * 16;    // 0,16,32,48
  const int prow = i0 + pr;
  const float si = s[z * NN + prow];
  const uint32_t* bmz = bmT + z * 131072;
  const float* dz = d + z * NN;

  const u16* BgZ = Bg + ((size_t)z << 20);
  const int ofb = ot * 16 + wave * 4;   // wave's first o-frag (of index)

  f32x4 acc[4][4];
#pragma unroll
  for (int f = 0; f < 4; ++f)
#pragma unroll
    for (int j = 0; j < 4; ++j) acc[f][j] = (f32x4){0.f, 0.f, 0.f, 0.f};

  // P write offsets (u16 units), fixed per thread up to parity
  const int prc = pr & 15, pch = pr >> 4;
  const int ph = ks >> 5, pq = (ks >> 3) & 3;   // pq in {0,2}
  const int pwoff0 = ph * 2048 + pch * 512 +
                     (prc * 4 + (pq ^ ((prc >> 1) & 3))) * 8;
  const int pwoff1 = ph * 2048 + pch * 512 +
                     (prc * 4 + ((pq + 1) ^ ((prc >> 1) & 3))) * 8;
  const int fslot = ln16 * 4 + (quad ^ ((ln16 >> 1) & 3));

  // prefetch mask word + d values for kt=0
  uint32_t wcur = bmz[(ks >> 5) * 2048 + prow];
  float4 dcur[4];
#pragma unroll
  for (int g = 0; g < 4; ++g) dcur[g] = *(const float4*)&dz[ks + g * 4];

  float lsum = 0.f;
  int par = 0;

  for (int kt = 0; kt < NN; kt += 64, par ^= 1) {
    const int kc0 = kt >> 5;

    // ---- 1. P-gen: 16 values from prefetched regs ----
    uint32_t bits16 = wcur >> (ks & 16);
    u16 pk[16];
#pragma unroll
    for (int g = 0; g < 4; ++g) {
      float4 dq = dcur[g];
#pragma unroll
      for (int e = 0; e < 4; ++e) {
        float x = si + felem(dq, e);
        float xm = fmaxf(x, 0.2f * x);
        float p = ((bits16 >> (g * 4 + e)) & 1u) ? 0.f : __expf(xm);
        lsum += p;
        pk[g * 4 + e] = f2bf(p);
      }
    }
    u16* Pbuf = &Plds[par][0];
    *(int4*)(Pbuf + pwoff0) = *(int4*)&pk[0];
    *(int4*)(Pbuf + pwoff1) = *(int4*)&pk[8];

    __syncthreads();  // the ONLY barrier in the K-loop (dbuf covers WAR)

    // ---- 2. B-frags direct from global (8 x dwordx4, L2-hot) ----
    bf16x8 bfr[2][4];
#pragma unroll
    for (int h = 0; h < 2; ++h)
#pragma unroll
      for (int j = 0; j < 4; ++j)
        bfr[h][j] = *(const bf16x8*)&BgZ[(((size_t)(kc0 + h) * 32) + ofb + j) *
                                             512 + lane * 8];

    // ---- 3. A-frags from LDS ----
    bf16x8 af[2][4];
#pragma unroll
    for (int h = 0; h < 2; ++h)
#pragma unroll
      for (int f = 0; f < 4; ++f)
        af[h][f] = *(const bf16x8*)(Pbuf + h * 2048 + f * 512 + fslot * 8);

    // ---- 4. prefetch next iter's mask/d (overlaps MFMA) ----
    if (kt + 64 < NN) {
      wcur = bmz[(((kt + 64) >> 5) + (ks >> 5)) * 2048 + prow];
#pragma unroll
      for (int g = 0; g < 4; ++g)
        dcur[g] = *(const float4*)&dz[kt + 64 + ks + g * 4];
    }

    // ---- 5. MFMA: 2 halves x 4 i-frags x 4 j-frags ----
#pragma unroll
    for (int h = 0; h < 2; ++h)
#pragma unroll
      for (int f = 0; f < 4; ++f)
#pragma unroll
        for (int j = 0; j < 4; ++j)
          acc[f][j] = __builtin_amdgcn_mfma_f32_16x16x32_bf16(af[h][f],
                                                              bfr[h][j],
                                                              acc[f][j], 0, 0, 0);
  }

  // ---- row sums -> 1/l ----
  lpart[pr * 4 + (t & 3)] = lsum;
  __syncthreads();
  if (t < 64) {
    const float* lp = &lpart[t * 4];
    linv_lds[t] = 1.0f / ((lp[0] + lp[1]) + (lp[2] + lp[3]));
  }
  __syncthreads();

  // ---- epilogue: C/D layout col=ln16 (o), row=quad*4+r (i) ----
#pragma unroll
  for (int f = 0; f < 4; ++f) {
#pragma unroll
    for (int r = 0; r < 4; ++r) {
      int m = f * 16 + quad * 4 + r;
      float sc = linv_lds[m];
      float* ob = out + ((size_t)(z * NN) + i0 + m) * NF + ot * 256 + wave * 64;
#pragma unroll
      for (int j = 0; j < 4; ++j) ob[j * 16 + ln16] = acc[f][j][r] * sc;
    }
  }
}

// ---------------------------------------------------------------------------
// launch
// ---------------------------------------------------------------------------
extern "C" void kernel_launch(void* const* d_in, const int* in_sizes, int n_in,
                              void* d_out, int out_size, void* d_ws,
                              size_t ws_size, hipStream_t stream) {
  const float* text  = (const float*)d_in[0];   // [8,2048,512] fp32
  const int*   adj   = (const int*)d_in[1];     // [8,2048,2048] int32
  const float* W     = (const float*)d_in[2];   // [512,512] fp32
  const float* bias  = (const float*)d_in[3];   // [512] fp32
  const float* a_src = (const float*)d_in[4];   // [512] fp32
  const float* a_dst = (const float*)d_in[5];   // [512] fp32
  float* out = (float*)d_out;                   // [8,2048,512] fp32

  // ws layout (bytes), ~38.4 MB
  char* ws = (char*)d_ws;
  u16*      text_bf = (u16*)(ws + 0);            // 16,777,216
  u16*      Wt      = (u16*)(ws + 16777216);     //    524,288
  u16*      Bg      = (u16*)(ws + 17301504);     // 16,777,216  frag-major
  float*    s       = (float*)(ws + 34078720);   //     65,536
  float*    d       = (float*)(ws + 34144256);   //     65,536
  uint32_t* bmT     = (uint32_t*)(ws + 34209792);// 4,194,304   transposed bits

  hipMemsetAsync(s, 0, 131072, stream);          // zero s,d (contiguous)

  conv_kernel<<<9216, 256, 0, stream>>>(text, W, text_bf, Wt);
  pack_kernel<<<4096, 256, 0, stream>>>(adj, bmT);

  gemm1_kernel<<<512, 256, 0, stream>>>(Wt, text_bf, bias, a_src, a_dst, Bg, s, d);

  fused_attn_kernel<<<512, 256, 0, stream>>>(bmT, s, d, Bg, out);
}